// Round 2
// baseline (76.252 us; speedup 1.0000x reference)
//
#include <hip/hip_runtime.h>

// VariationalQHead, 4 qubits, BATCH=1048576. Inputs/outputs are float32.
//
// Analytic reduction: circuit = RY-layer (product state) followed by only
// diagonal (RZ) and permutation (CNOT) ops => monomial unitary => final
// probabilities are a permutation of the initial product probabilities and
// `params` drops out entirely (phases cancel in |psi|^2).
//
// Bit propagation through CNOT(0,1),(1,2),(2,3),(3,0) on initial bits
// (i,j,k,l):  final = (j^k^l, i^j, i^j^k, i^j^k^l).  With independent
// initial qubits and E[(-1)^{b_q}] = cos(x_q) =: c_q:
//   out0 = c1*c2*c3, out1 = c0*c1, out2 = c0*c1*c2, out3 = c0*c1*c2*c3.

__global__ __launch_bounds__(256) void qhead_kernel(
    const float4* __restrict__ x,   // [B] float4: x[b] = (x0,x1,x2,x3)
    float4* __restrict__ out,       // [B] float4: expectations
    int n) {
  int idx = blockIdx.x * blockDim.x + threadIdx.x;
  if (idx >= n) return;

  float4 v = x[idx];
  float c0 = __cosf(v.x);
  float c1 = __cosf(v.y);
  float c2 = __cosf(v.z);
  float c3 = __cosf(v.w);

  float4 o;
  o.y = c0 * c1;        // <Z1> = c0 c1
  o.z = o.y * c2;       // <Z2> = c0 c1 c2
  o.w = o.z * c3;       // <Z3> = c0 c1 c2 c3
  o.x = c1 * c2 * c3;   // <Z0> = c1 c2 c3
  out[idx] = o;
}

extern "C" void kernel_launch(void* const* d_in, const int* in_sizes, int n_in,
                              void* d_out, int out_size, void* d_ws, size_t ws_size,
                              hipStream_t stream) {
  (void)n_in; (void)d_ws; (void)ws_size; (void)out_size;
  // d_in[0] = x [B,4] float32; d_in[1] = params [B,4] float32 (unused).
  const int B = in_sizes[0] / 4;   // 1048576
  const float4* x = reinterpret_cast<const float4*>(d_in[0]);
  float4* out = reinterpret_cast<float4*>(d_out);

  const int block = 256;
  const int grid = (B + block - 1) / block;
  qhead_kernel<<<grid, block, 0, stream>>>(x, out, B);
}